// Round 5
// baseline (21517.934 us; speedup 1.0000x reference)
//
#include <hip/hip_runtime.h>
#include <hip/hip_fp16.h>

// GetTopic: biLSTM (B=32,S=512,W=1024,HP=512) -> per-utterance segment max ->
// topic softmax (T=100) -> weighted gather. Inputs/outputs fp32 (probe-
// confirmed in R4; runtime probe retained for safety).
//
// R5 vs R4 (absmax 0.19140625 vs thr 0.19125 — one ulp over):
//  - Dominant error (bf16 h -> pool -> logits) eliminated: k_step atomicMax's
//    the fp32 h into mp directly (int-punned; valid for h>0 with 0 floor).
//    k_pool deleted.
//  - G fp32 when ws_size >= 176,702,464 B (serial-dir layout, 168.5 MiB,
//    proven-safe bound); fp16-G fallback at 104.5 MiB otherwise.
//  - Hs bf16 -> fp16 (matmul-path h noise /8, free).
// Dirs run serially (G buffer reused); stream order is the timestep barrier.

typedef unsigned short u16;
typedef unsigned int   u32;

__device__ __forceinline__ float bf2f(u16 u) { return __uint_as_float(((u32)u) << 16); }
__device__ __forceinline__ u16 f2bf(float f) {
  u32 u = __float_as_uint(f);
  u32 r = u + 0x7FFFu + ((u >> 16) & 1u);   // RNE
  return (u16)(r >> 16);
}
__device__ __forceinline__ float sigm(float x) { return 1.f / (1.f + expf(-x)); }

// dtype-adaptive element loads (index = flat element index)
__device__ __forceinline__ float ldF(const void* p, size_t i, int isBF) {
  return isBF ? bf2f(((const u16*)p)[i]) : ((const float*)p)[i];
}
__device__ __forceinline__ int ldI(const void* p, int i, int is64) {
  return is64 ? (int)((const u32*)p)[(size_t)2 * i]   // low word (values fit int32)
              : ((const int*)p)[i];
}

// ---------------------------------------------------------------------------
// Probe: decide input storage formats from raw bits (see R4 notes).
// flags[0]: 1 = float tensors bf16, 0 = fp32.  flags[1]: 1 = ids int64.
// ---------------------------------------------------------------------------
__global__ __launch_bounds__(256) void k_probe(
    const u32* __restrict__ X, const u32* __restrict__ U, u32* __restrict__ flags)
{
  __shared__ int cnt[2];
  if (threadIdx.x == 0) { cnt[0] = 0; cnt[1] = 0; }
  __syncthreads();
  int c0 = 0;
  for (int i = threadIdx.x; i < 1024; i += 256) {
    const u32 e = (X[i] >> 7) & 0xFFu;
    if (e >= 112u && e <= 143u) c0++;
  }
  int c1 = 0;
  {
    const u32 w = U[2 * threadIdx.x + 1];
    if (w == 0u || w == 0xFFFFFFFFu) c1++;
  }
  atomicAdd(&cnt[0], c0);
  atomicAdd(&cnt[1], c1);
  __syncthreads();
  if (threadIdx.x == 0) {
    flags[0] = (cnt[0] >= 512) ? 1u : 0u;
    flags[1] = (cnt[1] >= 128) ? 1u : 0u;
  }
}

// ---------------------------------------------------------------------------
// Phase 1 (per dir): G[s][n][b] = x @ Wih^T + (bih+bhh), fp32 (or fp16 if
// gHalf). GEMM M=16384 (m=s*32+b), N=2048, K=1024. 64x64 tiles, 4x4/thread.
// ---------------------------------------------------------------------------
__global__ __launch_bounds__(256) void k_xproj(
    const void* __restrict__ X, const void* __restrict__ Wih,
    const void* __restrict__ bih, const void* __restrict__ bhh,
    void* __restrict__ Gv, const u32* __restrict__ flags, int gHalf)
{
  const int isBF = (int)flags[0];
  const int m0 = blockIdx.x * 64;
  const int n0 = blockIdx.y * 64;
  __shared__ float Asl[32][68];
  __shared__ float Bsl[32][68];
  const int tid = threadIdx.x;
  const int tx = tid & 15, ty = tid >> 4;
  const int lrow = tid >> 2;
  const int lkg  = (tid & 3) * 8;
  const int am = m0 + lrow;
  const int ab = am & 31, as_ = am >> 5;           // m = s*32 + b
  const size_t arow = ((size_t)ab * 512 + as_) * 1024;
  const size_t brow = (size_t)(n0 + lrow) * 1024;
  float acc[4][4] = {{0.f, 0.f, 0.f, 0.f}};
  for (int k0 = 0; k0 < 1024; k0 += 32) {
    float a8[8], b8[8];
    if (isBF) {
      const u16* Xh = (const u16*)X;
      const u16* Wh = (const u16*)Wih;
      uint4 va = *(const uint4*)(Xh + arow + k0 + lkg);
      uint4 vb = *(const uint4*)(Wh + brow + k0 + lkg);
      const u32 wa[4] = {va.x, va.y, va.z, va.w};
      const u32 wb[4] = {vb.x, vb.y, vb.z, vb.w};
#pragma unroll
      for (int q = 0; q < 4; ++q) {
        a8[2 * q]     = __uint_as_float(wa[q] << 16);
        a8[2 * q + 1] = __uint_as_float(wa[q] & 0xFFFF0000u);
        b8[2 * q]     = __uint_as_float(wb[q] << 16);
        b8[2 * q + 1] = __uint_as_float(wb[q] & 0xFFFF0000u);
      }
    } else {
      const float* Xf = (const float*)X;
      const float* Wf = (const float*)Wih;
      const float4 xa0 = *(const float4*)(Xf + arow + k0 + lkg);
      const float4 xa1 = *(const float4*)(Xf + arow + k0 + lkg + 4);
      const float4 xb0 = *(const float4*)(Wf + brow + k0 + lkg);
      const float4 xb1 = *(const float4*)(Wf + brow + k0 + lkg + 4);
      a8[0] = xa0.x; a8[1] = xa0.y; a8[2] = xa0.z; a8[3] = xa0.w;
      a8[4] = xa1.x; a8[5] = xa1.y; a8[6] = xa1.z; a8[7] = xa1.w;
      b8[0] = xb0.x; b8[1] = xb0.y; b8[2] = xb0.z; b8[3] = xb0.w;
      b8[4] = xb1.x; b8[5] = xb1.y; b8[6] = xb1.z; b8[7] = xb1.w;
    }
#pragma unroll
    for (int q = 0; q < 8; ++q) {
      Asl[lkg + q][lrow] = a8[q];
      Bsl[lkg + q][lrow] = b8[q];
    }
    __syncthreads();
#pragma unroll
    for (int k = 0; k < 32; ++k) {
      const float4 av = *(const float4*)&Asl[k][ty * 4];
      const float4 bv = *(const float4*)&Bsl[k][tx * 4];
      float a4[4] = {av.x, av.y, av.z, av.w};
      float b4[4] = {bv.x, bv.y, bv.z, bv.w};
#pragma unroll
      for (int i = 0; i < 4; ++i)
#pragma unroll
        for (int j = 0; j < 4; ++j)
          acc[i][j] = fmaf(a4[i], b4[j], acc[i][j]);
    }
    __syncthreads();
  }
  float bias[4];
#pragma unroll
  for (int j = 0; j < 4; ++j) {
    int n = n0 + tx * 4 + j;
    bias[j] = ldF(bih, n, isBF) + ldF(bhh, n, isBF);
  }
  const int mb = m0 + ty * 4;
  const int b0 = mb & 31, ss = mb >> 5;
#pragma unroll
  for (int j = 0; j < 4; ++j) {
    const int n = n0 + tx * 4 + j;
    const size_t off = ((size_t)ss * 2048 + n) * 32 + b0;
    if (gHalf) {
      ushort4 pk;
      pk.x = __half_as_ushort(__float2half(acc[0][j] + bias[j]));
      pk.y = __half_as_ushort(__float2half(acc[1][j] + bias[j]));
      pk.z = __half_as_ushort(__float2half(acc[2][j] + bias[j]));
      pk.w = __half_as_ushort(__float2half(acc[3][j] + bias[j]));
      *(uint2*)((u16*)Gv + off) = *(uint2*)&pk;
    } else {
      float4 pk;
      pk.x = acc[0][j] + bias[j]; pk.y = acc[1][j] + bias[j];
      pk.z = acc[2][j] + bias[j]; pk.w = acc[3][j] + bias[j];
      *(float4*)((float*)Gv + off) = pk;
    }
  }
}

// ---------------------------------------------------------------------------
// Phase 2: one launch per timestep per dir (stream order = barrier). 64 WGs;
// WG = 8 hidden units; thread = (b = tid&31, jl = tid>>5). h_prev fp16 in
// LDS. h (fp32, pre-quantization) is atomicMax'd into mp (segment max fused,
// int-punned: valid since only h>0 updates and floor is 0).
// ---------------------------------------------------------------------------
__global__ __launch_bounds__(256) void k_step(
    const void* __restrict__ Gv, const void* __restrict__ Whh,
    u16* __restrict__ Hs, float* __restrict__ CS, float* __restrict__ mp,
    const void* __restrict__ uid, int t, int dir,
    const u32* __restrict__ flags, int gHalf)
{
  __shared__ u32 hl2[32 * 261];
  const int isBF = (int)flags[0];
  const int is64 = (int)flags[1];
  const int tid = threadIdx.x;
  const int j0 = (int)blockIdx.x * 8;
  const int sidx = dir ? (511 - t) : t;
  const int b = tid & 31, jl = tid >> 5;
  const int j = j0 + jl;

  if (t > 0) {
    const int sprev = dir ? (sidx + 1) : (sidx - 1);
    const u32* hsrc = (const u32*)Hs + (size_t)(dir * 512 + sprev) * 8192;
    for (int i = tid; i < 8192; i += 256)
      hl2[(i >> 8) * 261 + (i & 255)] = hsrc[i];
  }
  __syncthreads();

  float a0, a1, a2, a3;
  {
    const size_t gb = (size_t)sidx * 2048;
    if (gHalf) {
      const __half* G = (const __half*)Gv;
      a0 = __half2float(G[(gb + 0 * 512 + j) * 32 + b]);
      a1 = __half2float(G[(gb + 1 * 512 + j) * 32 + b]);
      a2 = __half2float(G[(gb + 2 * 512 + j) * 32 + b]);
      a3 = __half2float(G[(gb + 3 * 512 + j) * 32 + b]);
    } else {
      const float* G = (const float*)Gv;
      a0 = G[(gb + 0 * 512 + j) * 32 + b];
      a1 = G[(gb + 1 * 512 + j) * 32 + b];
      a2 = G[(gb + 2 * 512 + j) * 32 + b];
      a3 = G[(gb + 3 * 512 + j) * 32 + b];
    }
  }

  if (t > 0) {
    const u32* hrow = hl2 + b * 261;
    if (isBF) {
      const u32* wb = (const u32*)Whh;   // 2 bf16 per u32, row stride 256
      const u32* w0 = wb + (size_t)(0 * 512 + j) * 256;
      const u32* w1 = wb + (size_t)(1 * 512 + j) * 256;
      const u32* w2 = wb + (size_t)(2 * 512 + j) * 256;
      const u32* w3 = wb + (size_t)(3 * 512 + j) * 256;
      for (int kk = 0; kk < 256; ++kk) {
        const u32 hw = hrow[kk];
        const float h0 = __half2float(__ushort_as_half((u16)(hw & 0xFFFFu)));
        const float h1 = __half2float(__ushort_as_half((u16)(hw >> 16)));
        u32 ww;
        ww = w0[kk];
        a0 = fmaf(h0, __uint_as_float(ww << 16), a0);
        a0 = fmaf(h1, __uint_as_float(ww & 0xFFFF0000u), a0);
        ww = w1[kk];
        a1 = fmaf(h0, __uint_as_float(ww << 16), a1);
        a1 = fmaf(h1, __uint_as_float(ww & 0xFFFF0000u), a1);
        ww = w2[kk];
        a2 = fmaf(h0, __uint_as_float(ww << 16), a2);
        a2 = fmaf(h1, __uint_as_float(ww & 0xFFFF0000u), a2);
        ww = w3[kk];
        a3 = fmaf(h0, __uint_as_float(ww << 16), a3);
        a3 = fmaf(h1, __uint_as_float(ww & 0xFFFF0000u), a3);
      }
    } else {
      const float* wb = (const float*)Whh;  // row stride 512 floats
      const float2* w0 = (const float2*)(wb + (size_t)(0 * 512 + j) * 512);
      const float2* w1 = (const float2*)(wb + (size_t)(1 * 512 + j) * 512);
      const float2* w2 = (const float2*)(wb + (size_t)(2 * 512 + j) * 512);
      const float2* w3 = (const float2*)(wb + (size_t)(3 * 512 + j) * 512);
      for (int kk = 0; kk < 256; ++kk) {
        const u32 hw = hrow[kk];
        const float h0 = __half2float(__ushort_as_half((u16)(hw & 0xFFFFu)));
        const float h1 = __half2float(__ushort_as_half((u16)(hw >> 16)));
        float2 ww;
        ww = w0[kk]; a0 = fmaf(h0, ww.x, a0); a0 = fmaf(h1, ww.y, a0);
        ww = w1[kk]; a1 = fmaf(h0, ww.x, a1); a1 = fmaf(h1, ww.y, a1);
        ww = w2[kk]; a2 = fmaf(h0, ww.x, a2); a2 = fmaf(h1, ww.y, a2);
        ww = w3[kk]; a3 = fmaf(h0, ww.x, a3); a3 = fmaf(h1, ww.y, a3);
      }
    }
  }

  float c = (t > 0) ? CS[(size_t)dir * 16384 + j * 32 + b] : 0.f;
  const float ig = sigm(a0), fg = sigm(a1);
  const float gg = tanhf(a2), og = sigm(a3);
  c = fg * c + ig * gg;
  CS[(size_t)dir * 16384 + j * 32 + b] = c;
  const float h = og * tanhf(c);
  Hs[(size_t)(dir * 512 + sidx) * 16384 + b * 512 + j] = __half_as_ushort(__float2half(h));

  // fused fp32 segment max (reference: max over uid==u+1, clamped at 0)
  const int id = ldI(uid, b * 512 + sidx, is64);
  if (id > 0 && h > 0.f)
    atomicMax((int*)&mp[(size_t)(b * 32 + (id - 1)) * 1024 + dir * 512 + j],
              __float_as_int(h));
}

// ---------------------------------------------------------------------------
// Phase 4a: topic_weights -> twT[k][t] fp32, bias -> fp32.
// ---------------------------------------------------------------------------
__global__ __launch_bounds__(256) void k_prep(
    const void* __restrict__ tw, const void* __restrict__ tb,
    float* __restrict__ twT, float* __restrict__ biasT, const u32* __restrict__ flags)
{
  const int isBF = (int)flags[0];
  const int idx = blockIdx.x * 256 + threadIdx.x;
  if (idx < 102400) {
    const int t = idx >> 10, k = idx & 1023;
    twT[k * 100 + t] = ldF(tw, idx, isBF);
  } else if (idx < 102500) {
    biasT[idx - 102400] = ldF(tb, idx - 102400, isBF);
  }
}

// ---------------------------------------------------------------------------
// Phase 4: per (b,u): logits(100) -> softmax -> emb row (fp32).
// ---------------------------------------------------------------------------
__global__ __launch_bounds__(256) void k_topic(
    const float* __restrict__ mp, const float* __restrict__ twT,
    const float* __restrict__ biasT, const void* __restrict__ table,
    float* __restrict__ emb, const u32* __restrict__ flags)
{
  const int isBF = (int)flags[0];
  const int bu = blockIdx.x;
  const int tid = threadIdx.x;
  __shared__ float lrow[1024];
  __shared__ float red[128];
  __shared__ float parr[128];
  for (int i = tid; i < 1024; i += 256) lrow[i] = mp[(size_t)bu * 1024 + i];
  __syncthreads();
  float lacc = -1e30f;
  if (tid < 100) {
    lacc = biasT[tid];
    for (int k = 0; k < 1024; ++k) lacc = fmaf(lrow[k], twT[k * 100 + tid], lacc);
  }
  if (tid < 128) red[tid] = (tid < 100) ? lacc : -1e30f;
  __syncthreads();
  for (int off = 64; off > 0; off >>= 1) {
    if (tid < off) red[tid] = fmaxf(red[tid], red[tid + off]);
    __syncthreads();
  }
  const float mxv = red[0];
  __syncthreads();
  const float e = (tid < 100) ? expf(lacc - mxv) : 0.f;
  if (tid < 128) red[tid] = e;
  __syncthreads();
  for (int off = 64; off > 0; off >>= 1) {
    if (tid < off) red[tid] += red[tid + off];
    __syncthreads();
  }
  const float inv = 1.f / red[0];
  if (tid < 128) parr[tid] = e * inv;
  __syncthreads();
#pragma unroll
  for (int r = 0; r < 4; ++r) {
    const int w = tid + 256 * r;
    float a = 0.f;
    for (int t = 0; t < 100; ++t)
      a = fmaf(parr[t], ldF(table, (size_t)t * 1024 + w, isBF), a);
    emb[(size_t)bu * 1024 + w] = a;
  }
}

// ---------------------------------------------------------------------------
// Phase 5: out = emb[b][clip(|uid|-1,0,31)][w] * {1,2,0}. Dtype by flag.
// ---------------------------------------------------------------------------
__global__ __launch_bounds__(256) void k_out(
    const float* __restrict__ emb, const void* __restrict__ uid,
    void* __restrict__ outv, const u32* __restrict__ flags)
{
  const int isBF = (int)flags[0];
  const int is64 = (int)flags[1];
  const int idx = blockIdx.x * 256 + threadIdx.x;
  const int w = idx & 1023;
  const int s = (idx >> 10) & 511;
  const int b = idx >> 19;
  const int id = ldI(uid, b * 512 + s, is64);
  const float wt = (id > 0) ? 1.f : ((id < 0) ? 2.f : 0.f);
  int au = (id < 0) ? (-id - 1) : (id - 1);
  au = max(0, min(31, au));
  const float v = emb[(size_t)(b * 32 + au) * 1024 + w] * wt;
  if (isBF) ((u16*)outv)[idx] = f2bf(v);
  else      ((float*)outv)[idx] = v;
}

// ---------------------------------------------------------------------------
// ws layouts (serial dirs; G reused across dirs):
//  fp32-G (ws >= 176,702,464 B): G 128Mi | Hs 32Mi | mp 4Mi | emb 4Mi |
//    twT 400Ki | biasT | CS 128Ki | flags            total ~168.5 MiB
//  fp16-G fallback: G 64Mi | ... same tail           total ~104.5 MiB
// ---------------------------------------------------------------------------
extern "C" void kernel_launch(void* const* d_in, const int* in_sizes, int n_in,
                              void* d_out, int out_size, void* d_ws, size_t ws_size,
                              hipStream_t stream) {
  (void)in_sizes; (void)n_in; (void)out_size;
  const void* X    = d_in[0];
  const void* uid  = d_in[1];
  const void* Wihf = d_in[2];
  const void* Whhf = d_in[3];
  const void* bihf = d_in[4];
  const void* bhhf = d_in[5];
  const void* Wihb = d_in[6];
  const void* Whhb = d_in[7];
  const void* bihb = d_in[8];
  const void* bhhb = d_in[9];
  const void* tw   = d_in[10];
  const void* tb   = d_in[11];
  const void* tt   = d_in[12];
  char* ws = (char*)d_ws;

  const int gHalf = (ws_size >= 176702464ull) ? 0 : 1;
  const size_t gBytes = gHalf ? 67108864ull : 134217728ull;
  const size_t oHs = gBytes;
  const size_t omp = oHs + 33554432ull;
  const size_t oem = omp + 4194304ull;
  const size_t otw = oem + 4194304ull;
  const size_t obi = otw + 409600ull;
  const size_t oCS = obi + 512ull;
  const size_t oFL = oCS + 131072ull;

  void*  G     = (void*)(ws + 0);
  u16*   Hs    = (u16*)(ws + oHs);
  float* mp    = (float*)(ws + omp);
  float* emb   = (float*)(ws + oem);
  float* twT   = (float*)(ws + otw);
  float* biasT = (float*)(ws + obi);
  float* CS    = (float*)(ws + oCS);
  u32*   flags = (u32*)(ws + oFL);

  hipMemsetAsync(mp, 0, 4194304ull, stream);   // segment-max floor = 0
  k_probe<<<1, 256, 0, stream>>>((const u32*)X, (const u32*)uid, flags);

  // dir 0 (forward)
  k_xproj<<<dim3(256, 32), 256, 0, stream>>>(X, Wihf, bihf, bhhf, G, flags, gHalf);
  for (int t = 0; t < 512; ++t)
    k_step<<<64, 256, 0, stream>>>(G, Whhf, Hs, CS, mp, uid, t, 0, flags, gHalf);
  // dir 1 (backward) — G reused; stream order guarantees dir-0 steps done
  k_xproj<<<dim3(256, 32), 256, 0, stream>>>(X, Wihb, bihb, bhhb, G, flags, gHalf);
  for (int t = 0; t < 512; ++t)
    k_step<<<64, 256, 0, stream>>>(G, Whhb, Hs, CS, mp, uid, t, 1, flags, gHalf);

  k_prep<<<401, 256, 0, stream>>>(tw, tb, twT, biasT, flags);
  k_topic<<<1024, 256, 0, stream>>>(mp, twT, biasT, tt, emb, flags);
  k_out<<<65536, 256, 0, stream>>>(emb, uid, d_out, flags);
}

// Round 6
// 20125.513 us; speedup vs baseline: 1.0692x; 1.0692x over previous
//
#include <hip/hip_runtime.h>
#include <hip/hip_fp16.h>

// GetTopic: biLSTM (B=32,S=512,W=1024,HP=512) -> fused per-utterance segment
// max -> topic softmax (T=100) -> weighted gather. Inputs fp32 (probe kept).
//
// R6 vs R5 (21.5 ms, 1024 tiny k_step launches = ~17 ms of overhead):
//  - Persistent k_lstm per dir: 64 co-resident WGs, device-scope counter
//    barrier per timestep (release fence + acquire poll). Whh resident in
//    VGPRs as split-bf16 (hi+lo) MFMA fragments; recurrent matmul = 3 MFMA
//    chains (hh, hl, lh) => ~fp32 accuracy at MFMA speed.
//  - h history eliminated (mp max is fused per-step, R5-proven): h exchanged
//    via 128 KB ping-pong split-bf16 slab (L2-resident).
//  - G stays fp32 (serial dirs, reused) -> accuracy >= R5.

typedef unsigned short u16;
typedef unsigned int   u32;
typedef __attribute__((ext_vector_type(8))) short short8;
typedef __attribute__((ext_vector_type(4))) float float4v;

__device__ __forceinline__ float bf2f(u16 u) { return __uint_as_float(((u32)u) << 16); }
__device__ __forceinline__ u16 f2bf(float f) {
  u32 u = __float_as_uint(f);
  u32 r = u + 0x7FFFu + ((u >> 16) & 1u);   // RNE
  return (u16)(r >> 16);
}
__device__ __forceinline__ float sigm(float x) { return 1.f / (1.f + expf(-x)); }

__device__ __forceinline__ float ldF(const void* p, size_t i, int isBF) {
  return isBF ? bf2f(((const u16*)p)[i]) : ((const float*)p)[i];
}
__device__ __forceinline__ int ldI(const void* p, int i, int is64) {
  return is64 ? (int)((const u32*)p)[(size_t)2 * i] : ((const int*)p)[i];
}

union U4S8 { uint4 u; short8 s; u16 us[8]; };

// ---------------------------------------------------------------------------
// Probe: input storage formats from raw bits (R4/R5-proven).
// flags[0]: 1 = float tensors bf16, 0 = fp32.  flags[1]: 1 = ids int64.
// ---------------------------------------------------------------------------
__global__ __launch_bounds__(256) void k_probe(
    const u32* __restrict__ X, const u32* __restrict__ U, u32* __restrict__ flags)
{
  __shared__ int cnt[2];
  if (threadIdx.x == 0) { cnt[0] = 0; cnt[1] = 0; }
  __syncthreads();
  int c0 = 0;
  for (int i = threadIdx.x; i < 1024; i += 256) {
    const u32 e = (X[i] >> 7) & 0xFFu;
    if (e >= 112u && e <= 143u) c0++;
  }
  int c1 = 0;
  {
    const u32 w = U[2 * threadIdx.x + 1];
    if (w == 0u || w == 0xFFFFFFFFu) c1++;
  }
  atomicAdd(&cnt[0], c0);
  atomicAdd(&cnt[1], c1);
  __syncthreads();
  if (threadIdx.x == 0) {
    flags[0] = (cnt[0] >= 512) ? 1u : 0u;
    flags[1] = (cnt[1] >= 128) ? 1u : 0u;
  }
}

// ---------------------------------------------------------------------------
// Phase 1 (per dir): G[s][n][b] = x @ Wih^T + (bih+bhh), fp32 (fp16 if gHalf).
// GEMM M=16384 (m=s*32+b), N=2048, K=1024. 64x64 tiles, 4x4/thread. (R5)
// ---------------------------------------------------------------------------
__global__ __launch_bounds__(256) void k_xproj(
    const void* __restrict__ X, const void* __restrict__ Wih,
    const void* __restrict__ bih, const void* __restrict__ bhh,
    void* __restrict__ Gv, const u32* __restrict__ flags, int gHalf)
{
  const int isBF = (int)flags[0];
  const int m0 = blockIdx.x * 64;
  const int n0 = blockIdx.y * 64;
  __shared__ float Asl[32][68];
  __shared__ float Bsl[32][68];
  const int tid = threadIdx.x;
  const int tx = tid & 15, ty = tid >> 4;
  const int lrow = tid >> 2;
  const int lkg  = (tid & 3) * 8;
  const int am = m0 + lrow;
  const int ab = am & 31, as_ = am >> 5;           // m = s*32 + b
  const size_t arow = ((size_t)ab * 512 + as_) * 1024;
  const size_t brow = (size_t)(n0 + lrow) * 1024;
  float acc[4][4] = {{0.f, 0.f, 0.f, 0.f}};
  for (int k0 = 0; k0 < 1024; k0 += 32) {
    float a8[8], b8[8];
    if (isBF) {
      const u16* Xh = (const u16*)X;
      const u16* Wh = (const u16*)Wih;
      uint4 va = *(const uint4*)(Xh + arow + k0 + lkg);
      uint4 vb = *(const uint4*)(Wh + brow + k0 + lkg);
      const u32 wa[4] = {va.x, va.y, va.z, va.w};
      const u32 wb[4] = {vb.x, vb.y, vb.z, vb.w};
#pragma unroll
      for (int q = 0; q < 4; ++q) {
        a8[2 * q]     = __uint_as_float(wa[q] << 16);
        a8[2 * q + 1] = __uint_as_float(wa[q] & 0xFFFF0000u);
        b8[2 * q]     = __uint_as_float(wb[q] << 16);
        b8[2 * q + 1] = __uint_as_float(wb[q] & 0xFFFF0000u);
      }
    } else {
      const float* Xf = (const float*)X;
      const float* Wf = (const float*)Wih;
      const float4 xa0 = *(const float4*)(Xf + arow + k0 + lkg);
      const float4 xa1 = *(const float4*)(Xf + arow + k0 + lkg + 4);
      const float4 xb0 = *(const float4*)(Wf + brow + k0 + lkg);
      const float4 xb1 = *(const float4*)(Wf + brow + k0 + lkg + 4);
      a8[0] = xa0.x; a8[1] = xa0.y; a8[2] = xa0.z; a8[3] = xa0.w;
      a8[4] = xa1.x; a8[5] = xa1.y; a8[6] = xa1.z; a8[7] = xa1.w;
      b8[0] = xb0.x; b8[1] = xb0.y; b8[2] = xb0.z; b8[3] = xb0.w;
      b8[4] = xb1.x; b8[5] = xb1.y; b8[6] = xb1.z; b8[7] = xb1.w;
    }
#pragma unroll
    for (int q = 0; q < 8; ++q) {
      Asl[lkg + q][lrow] = a8[q];
      Bsl[lkg + q][lrow] = b8[q];
    }
    __syncthreads();
#pragma unroll
    for (int k = 0; k < 32; ++k) {
      const float4 av = *(const float4*)&Asl[k][ty * 4];
      const float4 bv = *(const float4*)&Bsl[k][tx * 4];
      float a4[4] = {av.x, av.y, av.z, av.w};
      float b4[4] = {bv.x, bv.y, bv.z, bv.w};
#pragma unroll
      for (int i = 0; i < 4; ++i)
#pragma unroll
        for (int j = 0; j < 4; ++j)
          acc[i][j] = fmaf(a4[i], b4[j], acc[i][j]);
    }
    __syncthreads();
  }
  float bias[4];
#pragma unroll
  for (int j = 0; j < 4; ++j) {
    int n = n0 + tx * 4 + j;
    bias[j] = ldF(bih, n, isBF) + ldF(bhh, n, isBF);
  }
  const int mb = m0 + ty * 4;
  const int b0 = mb & 31, ss = mb >> 5;
#pragma unroll
  for (int j = 0; j < 4; ++j) {
    const int n = n0 + tx * 4 + j;
    const size_t off = ((size_t)ss * 2048 + n) * 32 + b0;
    if (gHalf) {
      ushort4 pk;
      pk.x = __half_as_ushort(__float2half(acc[0][j] + bias[j]));
      pk.y = __half_as_ushort(__float2half(acc[1][j] + bias[j]));
      pk.z = __half_as_ushort(__float2half(acc[2][j] + bias[j]));
      pk.w = __half_as_ushort(__float2half(acc[3][j] + bias[j]));
      *(uint2*)((u16*)Gv + off) = *(uint2*)&pk;
    } else {
      float4 pk;
      pk.x = acc[0][j] + bias[j]; pk.y = acc[1][j] + bias[j];
      pk.z = acc[2][j] + bias[j]; pk.w = acc[3][j] + bias[j];
      *(float4*)((float*)Gv + off) = pk;
    }
  }
}

// ---------------------------------------------------------------------------
// Phase 2: persistent recurrence, one launch per dir. 64 WGs x 256 threads
// (1 WG/CU by VGPR use -> all co-resident). WG owns 8 hidden units = 32 gate
// cols; wave (mt=wid&1: batch half, nt=wid>>1: col half) computes one
// 16x16 K=512 tile via 3 split-bf16 MFMA chains. h exchanged as split-bf16
// through 2x32KB ping-pong slabs; fp32 h atomicMax'd into mp (fused pool).
// Barrier: per-thread threadfence + syncthreads + tid0 release-add; tid0
// acquire-poll + syncthreads on the consumer side.
// ---------------------------------------------------------------------------
__global__ __launch_bounds__(256) void k_lstm(
    const void* __restrict__ Gv, const void* __restrict__ Whh,
    u16* __restrict__ Hhi, u16* __restrict__ Hlo,
    float* __restrict__ mp, const void* __restrict__ uid,
    unsigned* __restrict__ ctr, int dir,
    const u32* __restrict__ flags, int gHalf)
{
  __shared__ float gl[1024];          // [col32][b32] gate preacts
  const int isBF = (int)flags[0];
  const int is64 = (int)flags[1];
  const int tid = threadIdx.x;
  const int j0 = (int)blockIdx.x * 8;
  const int lane = tid & 63;
  const int wid = tid >> 6;
  const int mt = wid & 1, nt = wid >> 1;
  const int l15 = lane & 15;
  const int quad = lane >> 4;
  const int nl = nt * 16 + l15;        // col 0..31 within WG
  const int n = ((nl >> 3) * 512) + j0 + (nl & 7);   // global gate row/col

  // B-frags: split-bf16 of Whh row n. B[n=l15][k=quad*8+j].
  short8 bhi[16], blo[16];
#pragma unroll 1
  for (int kt = 0; kt < 16; ++kt) {
    const int k0 = kt * 32 + quad * 8;
    float w[8];
    if (isBF) {
      const u16* Wh = (const u16*)Whh;
#pragma unroll
      for (int jj = 0; jj < 8; ++jj) w[jj] = bf2f(Wh[(size_t)n * 512 + k0 + jj]);
    } else {
      const float* Wf = (const float*)Whh;
      const float4 w0 = *(const float4*)(Wf + (size_t)n * 512 + k0);
      const float4 w1 = *(const float4*)(Wf + (size_t)n * 512 + k0 + 4);
      w[0] = w0.x; w[1] = w0.y; w[2] = w0.z; w[3] = w0.w;
      w[4] = w1.x; w[5] = w1.y; w[6] = w1.z; w[7] = w1.w;
    }
    U4S8 ph, pl;
#pragma unroll
    for (int jj = 0; jj < 8; ++jj) {
      const u16 hi = f2bf(w[jj]);
      const float rem = w[jj] - bf2f(hi);   // exact (Sterbenz)
      ph.us[jj] = hi; pl.us[jj] = f2bf(rem);
    }
    bhi[kt] = ph.s; blo[kt] = pl.s;
  }

  const int b_a = mt * 16 + l15;        // A row = batch
  const int cb = tid & 31;              // consumer: batch
  const int ciu = tid >> 5;             // consumer: unit 0..7
  float c = 0.f;

  for (int t = 0; t < 512; ++t) {
    const int sidx = dir ? (511 - t) : t;
    if (t > 0) {
      if (tid == 0) {
        const unsigned target = 64u * (unsigned)t;
        while (__hip_atomic_load(ctr, __ATOMIC_ACQUIRE, __HIP_MEMORY_SCOPE_AGENT) < target)
          __builtin_amdgcn_s_sleep(1);
      }
      __syncthreads();
    }

    // C-init from G (4 consecutive batches per lane, col n)
    float4v acc_hh, acc_hl, acc_lh;
    {
      const size_t goff = ((size_t)sidx * 2048 + n) * 32 + mt * 16 + quad * 4;
      if (gHalf) {
        const __half* G = (const __half*)Gv;
        acc_hh.x = __half2float(G[goff + 0]);
        acc_hh.y = __half2float(G[goff + 1]);
        acc_hh.z = __half2float(G[goff + 2]);
        acc_hh.w = __half2float(G[goff + 3]);
      } else {
        const float4 gv = *(const float4*)((const float*)Gv + goff);
        acc_hh.x = gv.x; acc_hh.y = gv.y; acc_hh.z = gv.z; acc_hh.w = gv.w;
      }
      acc_hl.x = 0.f; acc_hl.y = 0.f; acc_hl.z = 0.f; acc_hl.w = 0.f;
      acc_lh.x = 0.f; acc_lh.y = 0.f; acc_lh.z = 0.f; acc_lh.w = 0.f;
    }

    if (t > 0) {
      const size_t abase = (size_t)((t - 1) & 1) * 16384 + (size_t)b_a * 512 + quad * 8;
      const u16* ah = Hhi + abase;
      const u16* al = Hlo + abase;
#pragma unroll
      for (int kt = 0; kt < 16; ++kt) {
        U4S8 va, vl;
        va.u = *(const uint4*)(ah + kt * 32);
        vl.u = *(const uint4*)(al + kt * 32);
        acc_hh = __builtin_amdgcn_mfma_f32_16x16x32_bf16(va.s, bhi[kt], acc_hh, 0, 0, 0);
        acc_hl = __builtin_amdgcn_mfma_f32_16x16x32_bf16(va.s, blo[kt], acc_hl, 0, 0, 0);
        acc_lh = __builtin_amdgcn_mfma_f32_16x16x32_bf16(vl.s, bhi[kt], acc_lh, 0, 0, 0);
      }
    }

    // exchange: D row (quad*4+r) = batch - mt*16, col l15 -> nl
    {
      const int base = nl * 32 + mt * 16 + quad * 4;
      gl[base + 0] = acc_hh.x + acc_hl.x + acc_lh.x;
      gl[base + 1] = acc_hh.y + acc_hl.y + acc_lh.y;
      gl[base + 2] = acc_hh.z + acc_hl.z + acc_lh.z;
      gl[base + 3] = acc_hh.w + acc_hl.w + acc_lh.w;
    }
    __syncthreads();

    {
      const float a0 = gl[(0 * 8 + ciu) * 32 + cb];
      const float a1 = gl[(1 * 8 + ciu) * 32 + cb];
      const float a2 = gl[(2 * 8 + ciu) * 32 + cb];
      const float a3 = gl[(3 * 8 + ciu) * 32 + cb];
      const float ig = sigm(a0), fg = sigm(a1);
      const float gg = tanhf(a2), og = sigm(a3);
      c = fg * c + ig * gg;
      const float h = og * tanhf(c);
      const u16 hh = f2bf(h);
      const float rem = h - bf2f(hh);
      const size_t so = (size_t)(t & 1) * 16384 + (size_t)cb * 512 + (j0 + ciu);
      Hhi[so] = hh;
      Hlo[so] = f2bf(rem);
      const int id = ldI(uid, cb * 512 + sidx, is64);
      if (id > 0 && h > 0.f)
        atomicMax((int*)&mp[(size_t)(cb * 32 + (id - 1)) * 1024 + dir * 512 + (j0 + ciu)],
                  __float_as_int(h));
    }
    __threadfence();       // drain h-slab writes to device coherence point
    __syncthreads();
    if (tid == 0)
      __hip_atomic_fetch_add(ctr, 1u, __ATOMIC_RELEASE, __HIP_MEMORY_SCOPE_AGENT);
  }
}

// ---------------------------------------------------------------------------
// Phase 4a: topic_weights -> twT[k][t] fp32, bias -> fp32.
// ---------------------------------------------------------------------------
__global__ __launch_bounds__(256) void k_prep(
    const void* __restrict__ tw, const void* __restrict__ tb,
    float* __restrict__ twT, float* __restrict__ biasT, const u32* __restrict__ flags)
{
  const int isBF = (int)flags[0];
  const int idx = blockIdx.x * 256 + threadIdx.x;
  if (idx < 102400) {
    const int t = idx >> 10, k = idx & 1023;
    twT[k * 100 + t] = ldF(tw, idx, isBF);
  } else if (idx < 102500) {
    biasT[idx - 102400] = ldF(tb, idx - 102400, isBF);
  }
}

// ---------------------------------------------------------------------------
// Phase 4: per (b,u): logits(100) -> softmax -> emb row (fp32).
// ---------------------------------------------------------------------------
__global__ __launch_bounds__(256) void k_topic(
    const float* __restrict__ mp, const float* __restrict__ twT,
    const float* __restrict__ biasT, const void* __restrict__ table,
    float* __restrict__ emb, const u32* __restrict__ flags)
{
  const int isBF = (int)flags[0];
  const int bu = blockIdx.x;
  const int tid = threadIdx.x;
  __shared__ float lrow[1024];
  __shared__ float red[128];
  __shared__ float parr[128];
  for (int i = tid; i < 1024; i += 256) lrow[i] = mp[(size_t)bu * 1024 + i];
  __syncthreads();
  float lacc = -1e30f;
  if (tid < 100) {
    lacc = biasT[tid];
    for (int k = 0; k < 1024; ++k) lacc = fmaf(lrow[k], twT[k * 100 + tid], lacc);
  }
  if (tid < 128) red[tid] = (tid < 100) ? lacc : -1e30f;
  __syncthreads();
  for (int off = 64; off > 0; off >>= 1) {
    if (tid < off) red[tid] = fmaxf(red[tid], red[tid + off]);
    __syncthreads();
  }
  const float mxv = red[0];
  __syncthreads();
  const float e = (tid < 100) ? expf(lacc - mxv) : 0.f;
  if (tid < 128) red[tid] = e;
  __syncthreads();
  for (int off = 64; off > 0; off >>= 1) {
    if (tid < off) red[tid] += red[tid + off];
    __syncthreads();
  }
  const float inv = 1.f / red[0];
  if (tid < 128) parr[tid] = e * inv;
  __syncthreads();
#pragma unroll
  for (int r = 0; r < 4; ++r) {
    const int w = tid + 256 * r;
    float a = 0.f;
    for (int t = 0; t < 100; ++t)
      a = fmaf(parr[t], ldF(table, (size_t)t * 1024 + w, isBF), a);
    emb[(size_t)bu * 1024 + w] = a;
  }
}

// ---------------------------------------------------------------------------
// Phase 5: out = emb[b][clip(|uid|-1,0,31)][w] * {1,2,0}. Dtype by flag.
// ---------------------------------------------------------------------------
__global__ __launch_bounds__(256) void k_out(
    const float* __restrict__ emb, const void* __restrict__ uid,
    void* __restrict__ outv, const u32* __restrict__ flags)
{
  const int isBF = (int)flags[0];
  const int is64 = (int)flags[1];
  const int idx = blockIdx.x * 256 + threadIdx.x;
  const int w = idx & 1023;
  const int s = (idx >> 10) & 511;
  const int b = idx >> 19;
  const int id = ldI(uid, b * 512 + s, is64);
  const float wt = (id > 0) ? 1.f : ((id < 0) ? 2.f : 0.f);
  int au = (id < 0) ? (-id - 1) : (id - 1);
  au = max(0, min(31, au));
  const float v = emb[(size_t)(b * 32 + au) * 1024 + w] * wt;
  if (isBF) ((u16*)outv)[idx] = f2bf(v);
  else      ((float*)outv)[idx] = v;
}

// ---------------------------------------------------------------------------
// ws layout (serial dirs; G reused):
//  fp32-G (ws >= 143e6 B; R5 proved >=176.7MB): G 128Mi | Hhi 64Ki | Hlo 64Ki
//    | mp 4Mi | emb 4Mi | twT 400Ki | biasT | ctr | flags   ~= 136.8 MiB
//  fp16-G fallback: G 64Mi + same tail ~= 72.8 MiB
// ---------------------------------------------------------------------------
extern "C" void kernel_launch(void* const* d_in, const int* in_sizes, int n_in,
                              void* d_out, int out_size, void* d_ws, size_t ws_size,
                              hipStream_t stream) {
  (void)in_sizes; (void)n_in; (void)out_size;
  const void* X    = d_in[0];
  const void* uid  = d_in[1];
  const void* Wihf = d_in[2];
  const void* Whhf = d_in[3];
  const void* bihf = d_in[4];
  const void* bhhf = d_in[5];
  const void* Wihb = d_in[6];
  const void* Whhb = d_in[7];
  const void* bihb = d_in[8];
  const void* bhhb = d_in[9];
  const void* tw   = d_in[10];
  const void* tb   = d_in[11];
  const void* tt   = d_in[12];
  char* ws = (char*)d_ws;

  const int gHalf = (ws_size >= 143000000ull) ? 0 : 1;
  const size_t gBytes = gHalf ? 67108864ull : 134217728ull;
  const size_t oHhi = gBytes;
  const size_t oHlo = oHhi + 65536ull;
  const size_t omp  = oHlo + 65536ull;
  const size_t oem  = omp + 4194304ull;
  const size_t otw  = oem + 4194304ull;
  const size_t obi  = otw + 409600ull;
  const size_t oct  = obi + 512ull;
  const size_t oFL  = oct + 512ull;

  void*  G     = (void*)(ws + 0);
  u16*   Hhi   = (u16*)(ws + oHhi);
  u16*   Hlo   = (u16*)(ws + oHlo);
  float* mp    = (float*)(ws + omp);
  float* emb   = (float*)(ws + oem);
  float* twT   = (float*)(ws + otw);
  float* biasT = (float*)(ws + obi);
  unsigned* ctr = (unsigned*)(ws + oct);
  u32*   flags = (u32*)(ws + oFL);

  hipMemsetAsync(mp, 0, 4194304ull, stream);    // segment-max floor = 0
  hipMemsetAsync(ctr, 0, 512ull, stream);       // barrier counters
  k_probe<<<1, 256, 0, stream>>>((const u32*)X, (const u32*)uid, flags);

  // dir 0 (forward)
  k_xproj<<<dim3(256, 32), 256, 0, stream>>>(X, Wihf, bihf, bhhf, G, flags, gHalf);
  k_lstm<<<64, 256, 0, stream>>>(G, Whhf, Hhi, Hlo, mp, uid, ctr, 0, flags, gHalf);
  // dir 1 (backward) — G reused (stream-ordered)
  k_xproj<<<dim3(256, 32), 256, 0, stream>>>(X, Wihb, bihb, bhhb, G, flags, gHalf);
  k_lstm<<<64, 256, 0, stream>>>(G, Whhb, Hhi, Hlo, mp, uid, ctr + 32, 1, flags, gHalf);

  k_prep<<<401, 256, 0, stream>>>(tw, tb, twT, biasT, flags);
  k_topic<<<1024, 256, 0, stream>>>(mp, twT, biasT, tt, emb, flags);
  k_out<<<65536, 256, 0, stream>>>(emb, uid, d_out, flags);
}